// Round 1
// baseline (280.577 us; speedup 1.0000x reference)
//
#include <hip/hip_runtime.h>

typedef __bf16 bf16_t;
typedef __bf16 bf16x8 __attribute__((ext_vector_type(8)));
typedef __bf16 bf16x4 __attribute__((ext_vector_type(4)));
typedef float f32x4 __attribute__((ext_vector_type(4)));

static constexpr int Bb = 4, Hh = 12, Nn = 1024, Cc = 768, HD = 64;
static constexpr int OUT0 = Bb * Nn * Cc;  // 3145728 floats

// ---------------- convert fp32 -> bf16 (x, qkv_w, proj_w) ----------------
__global__ __launch_bounds__(256) void convert_all(
    const float* __restrict__ x, const float* __restrict__ qw, const float* __restrict__ pw,
    bf16_t* __restrict__ xb, bf16_t* __restrict__ qwb, bf16_t* __restrict__ pwb) {
  const int NX = (Bb * Nn * Cc) / 4;  // 786432 float4s
  const int NQ = (3 * Cc * Cc) / 4;   // 442368
  int i = blockIdx.x * 256 + threadIdx.x;
  const float4* src;
  bf16_t* dst;
  int off;
  if (i < NX) { src = (const float4*)x; dst = xb; off = i; }
  else if (i < NX + NQ) { src = (const float4*)qw; dst = qwb; off = i - NX; }
  else { src = (const float4*)pw; dst = pwb; off = i - NX - NQ; }
  float4 v = src[off];
  bf16x4 o;
  o[0] = (bf16_t)v.x; o[1] = (bf16_t)v.y; o[2] = (bf16_t)v.z; o[3] = (bf16_t)v.w;
  *(bf16x4*)(dst + (size_t)off * 4) = o;
}

// ---------------- 128x128-tile bf16 MFMA GEMM, C[m,c] = A[m,:]*B[c,:] -----
// MODE 0: qkv projection epilogue (scatter to q_bf, k_bf, vT_bf)
// MODE 1: output projection epilogue (add bias, fp32 store)
template <int MODE>
__global__ __launch_bounds__(256) void gemm_bt(
    const bf16_t* __restrict__ A, const bf16_t* __restrict__ Bm, int N, int K,
    bf16_t* __restrict__ q_bf, bf16_t* __restrict__ k_bf, bf16_t* __restrict__ vT_bf,
    float* __restrict__ outF, const float* __restrict__ bias) {
  __shared__ bf16_t As[128 * 40];  // pad 32 -> 40 to spread LDS banks
  __shared__ bf16_t Bs[128 * 40];
  const int tid = threadIdx.x;
  const int lane = tid & 63;
  const int w = tid >> 6;
  const int wr = w >> 1, wc = w & 1;
  const int g = lane >> 4, r = lane & 15;
  const int ntiles = N >> 7;
  const int m0 = (blockIdx.x / ntiles) << 7;
  const int n0 = (blockIdx.x % ntiles) << 7;

  const f32x4 fz = {0.f, 0.f, 0.f, 0.f};
  f32x4 acc[4][4];
#pragma unroll
  for (int i = 0; i < 4; i++)
#pragma unroll
    for (int j = 0; j < 4; j++) acc[i][j] = fz;

  for (int k0 = 0; k0 < K; k0 += 32) {
#pragma unroll
    for (int p = 0; p < 2; p++) {
      int idx = tid + (p << 8);
      int row = idx >> 2;
      int kof = (idx & 3) << 3;
      *(bf16x8*)&As[row * 40 + kof] = *(const bf16x8*)&A[(size_t)(m0 + row) * K + k0 + kof];
      *(bf16x8*)&Bs[row * 40 + kof] = *(const bf16x8*)&Bm[(size_t)(n0 + row) * K + k0 + kof];
    }
    __syncthreads();
    bf16x8 af[4], bfv[4];
#pragma unroll
    for (int i = 0; i < 4; i++) af[i] = *(const bf16x8*)&As[(wr * 64 + i * 16 + r) * 40 + g * 8];
#pragma unroll
    for (int j = 0; j < 4; j++) bfv[j] = *(const bf16x8*)&Bs[(wc * 64 + j * 16 + r) * 40 + g * 8];
#pragma unroll
    for (int i = 0; i < 4; i++)
#pragma unroll
      for (int j = 0; j < 4; j++)
        acc[i][j] = __builtin_amdgcn_mfma_f32_16x16x32_bf16(af[i], bfv[j], acc[i][j], 0, 0, 0);
    __syncthreads();
  }

#pragma unroll
  for (int i = 0; i < 4; i++) {
#pragma unroll
    for (int j = 0; j < 4; j++) {
      int c = n0 + wc * 64 + j * 16 + r;
#pragma unroll
      for (int e = 0; e < 4; e++) {
        int mrow = m0 + wr * 64 + i * 16 + g * 4 + e;
        float val = acc[i][j][e];
        if constexpr (MODE == 0) {
          int which = c / 768;       // 0:q 1:k 2:v  (tiles never straddle)
          int cc = c - which * 768;
          int h = cc >> 6, d = cc & 63;
          int b = mrow >> 10, n = mrow & 1023;
          size_t bh = (size_t)(b * Hh + h);
          if (which == 0)      q_bf[(bh * Nn + n) * HD + d] = (bf16_t)val;
          else if (which == 1) k_bf[(bh * Nn + n) * HD + d] = (bf16_t)val;
          else                 vT_bf[(bh * HD + d) * Nn + n] = (bf16_t)val;
        } else {
          outF[(size_t)mrow * N + c] = val + bias[c];
        }
      }
    }
  }
}

// ---------------- QK^T * scale -> softmax -> cur_attn (output 1) ---------
// block: 256 thr (4 waves), 16 rows of one (b,h); wave w covers cols [256w,256w+256)
__global__ __launch_bounds__(256) void attn_softmax(
    const bf16_t* __restrict__ qb, const bf16_t* __restrict__ kb, float* __restrict__ cur) {
  const int bid = blockIdx.x;
  const int bh = bid >> 6, mt = bid & 63;
  const int lane = threadIdx.x & 63, w = threadIdx.x >> 6;
  const int g = lane >> 4, r = lane & 15;
  const int row0 = mt << 4;
  const bf16_t* qp = qb + ((size_t)bh * Nn + row0) * HD;
  const bf16_t* kp = kb + (size_t)bh * Nn * HD;
  bf16x8 a0 = *(const bf16x8*)&qp[r * HD + g * 8];
  bf16x8 a1 = *(const bf16x8*)&qp[r * HD + g * 8 + 32];
  const f32x4 fz = {0.f, 0.f, 0.f, 0.f};
  f32x4 acc[16];
#pragma unroll
  for (int t = 0; t < 16; t++) {
    int col = (w << 8) + (t << 4) + r;
    bf16x8 b0 = *(const bf16x8*)&kp[(size_t)col * HD + g * 8];
    bf16x8 b1 = *(const bf16x8*)&kp[(size_t)col * HD + g * 8 + 32];
    f32x4 z = __builtin_amdgcn_mfma_f32_16x16x32_bf16(a0, b0, fz, 0, 0, 0);
    acc[t] = __builtin_amdgcn_mfma_f32_16x16x32_bf16(a1, b1, z, 0, 0, 0);
  }
  const float scale = 0.125f;  // 1/sqrt(64)
  float mj[4] = {-3.0e38f, -3.0e38f, -3.0e38f, -3.0e38f};
#pragma unroll
  for (int t = 0; t < 16; t++)
#pragma unroll
    for (int e = 0; e < 4; e++) {
      acc[t][e] *= scale;
      mj[e] = fmaxf(mj[e], acc[t][e]);
    }
#pragma unroll
  for (int s = 1; s < 16; s <<= 1)
#pragma unroll
    for (int e = 0; e < 4; e++) mj[e] = fmaxf(mj[e], __shfl_xor(mj[e], s, 64));
  __shared__ float redmax[16][4];
  __shared__ float redsum[16][4];
  if (r == 0) {
#pragma unroll
    for (int e = 0; e < 4; e++) redmax[g * 4 + e][w] = mj[e];
  }
  __syncthreads();
  float rm[4];
#pragma unroll
  for (int e = 0; e < 4; e++) {
    float v = fmaxf(redmax[g * 4 + e][0], redmax[g * 4 + e][1]);
    rm[e] = fmaxf(v, fmaxf(redmax[g * 4 + e][2], redmax[g * 4 + e][3]));
  }
  float sj[4] = {0.f, 0.f, 0.f, 0.f};
#pragma unroll
  for (int t = 0; t < 16; t++)
#pragma unroll
    for (int e = 0; e < 4; e++) {
      float ev = __expf(acc[t][e] - rm[e]);
      acc[t][e] = ev;
      sj[e] += ev;
    }
#pragma unroll
  for (int s = 1; s < 16; s <<= 1)
#pragma unroll
    for (int e = 0; e < 4; e++) sj[e] += __shfl_xor(sj[e], s, 64);
  if (r == 0) {
#pragma unroll
    for (int e = 0; e < 4; e++) redsum[g * 4 + e][w] = sj[e];
  }
  __syncthreads();
  float inv[4];
#pragma unroll
  for (int e = 0; e < 4; e++)
    inv[e] = 1.f / (redsum[g * 4 + e][0] + redsum[g * 4 + e][1] +
                    redsum[g * 4 + e][2] + redsum[g * 4 + e][3]);
  float* op = cur + (size_t)bh * Nn * Nn;
#pragma unroll
  for (int t = 0; t < 16; t++) {
    int col = (w << 8) + (t << 4) + r;
#pragma unroll
    for (int e = 0; e < 4; e++)
      op[(size_t)(row0 + g * 4 + e) * Nn + col] = acc[t][e] * inv[e];
  }
}

// ---------------- per-(b,h,n) bias MLP -> {1+b0, b1, -b2/N, 0} -----------
__global__ __launch_bounds__(256) void bias_mlp(
    const bf16_t* __restrict__ qb, const bf16_t* __restrict__ kb,
    const float* __restrict__ w1, const float* __restrict__ b1,
    const float* __restrict__ w2, const float* __restrict__ b2,
    float* __restrict__ bias4) {
  __shared__ float w1s[32 * 129];
  __shared__ float qks[8][128];
  __shared__ float h1s[8][32];
  const int t = threadIdx.x;
#pragma unroll
  for (int p = 0; p < 16; p++) {
    int idx = p * 256 + t;  // 4096 floats of w1
    w1s[(idx >> 7) * 129 + (idx & 127)] = w1[idx];
  }
  const int rl = t >> 5, u = t & 31;
  const int rowg = blockIdx.x * 8 + rl;  // flat (b,h,n)
  {
    int i4 = u * 4;
    const bf16_t* src = (i4 < 64) ? (qb + (size_t)rowg * HD + i4)
                                  : (kb + (size_t)rowg * HD + (i4 - 64));
    bf16x4 vv = *(const bf16x4*)src;
#pragma unroll
    for (int z = 0; z < 4; z++) qks[rl][i4 + z] = (float)vv[z];
  }
  __syncthreads();
  float accv = b1[u];
#pragma unroll 8
  for (int i = 0; i < 128; i++) accv += qks[rl][i] * w1s[u * 129 + i];
  h1s[rl][u] = fmaxf(accv, 0.f);
  __syncthreads();
  if (u < 4) {
    float outv = 0.f;
    if (u < 3) {
      float s = b2[u];
#pragma unroll
      for (int j = 0; j < 32; j++) s += w2[u * 32 + j] * h1s[rl][j];
      float v = fabsf(s);
      outv = (u == 0) ? (1.f + v) : ((u == 1) ? v : -v * (1.f / (float)Nn));
    }
    bias4[(size_t)rowg * 4 + u] = outv;
  }
}

// ---------------- blended attn @ v (fused blend into A-fragment) ---------
// block: 256 thr (4 waves); wave w -> rows [64*mt + 16*w, +16), all 64 cols
__global__ __launch_bounds__(256) void blend_av(
    const float* __restrict__ cur, const float* __restrict__ prev,
    const float* __restrict__ bias4, const bf16_t* __restrict__ vT,
    bf16_t* __restrict__ oh) {
  const int bid = blockIdx.x;
  const int bh = bid >> 4, mt = bid & 15;
  const int lane = threadIdx.x & 63, w = threadIdx.x >> 6;
  const int g = lane >> 4, r = lane & 15;
  const int rowbase = (mt << 6) + (w << 4);
  const size_t aoff = (size_t)bh * Nn * Nn + (size_t)(rowbase + r) * Nn + g * 8;
  const float* cp = cur + aoff;
  const float* pp = prev + aoff;
  const float4 bv = *(const float4*)&bias4[(size_t)(bh * Nn + rowbase + r) * 4];
  const float b0 = bv.x, b1 = bv.y, b2 = bv.z;
  const bf16_t* vp = vT + (size_t)bh * HD * Nn;
  const f32x4 fz = {0.f, 0.f, 0.f, 0.f};
  f32x4 acc[4] = {fz, fz, fz, fz};
  for (int k0 = 0; k0 < Nn; k0 += 32) {
    float4 c0 = *(const float4*)(cp + k0);
    float4 c1 = *(const float4*)(cp + k0 + 4);
    float4 p0 = *(const float4*)(pp + k0);
    float4 p1 = *(const float4*)(pp + k0 + 4);
    bf16x8 a;
    a[0] = (bf16_t)(b0 * c0.x + b1 * p0.x + b2);
    a[1] = (bf16_t)(b0 * c0.y + b1 * p0.y + b2);
    a[2] = (bf16_t)(b0 * c0.z + b1 * p0.z + b2);
    a[3] = (bf16_t)(b0 * c0.w + b1 * p0.w + b2);
    a[4] = (bf16_t)(b0 * c1.x + b1 * p1.x + b2);
    a[5] = (bf16_t)(b0 * c1.y + b1 * p1.y + b2);
    a[6] = (bf16_t)(b0 * c1.z + b1 * p1.z + b2);
    a[7] = (bf16_t)(b0 * c1.w + b1 * p1.w + b2);
#pragma unroll
    for (int tt = 0; tt < 4; tt++) {
      bf16x8 bvv = *(const bf16x8*)&vp[(size_t)((tt << 4) + r) * Nn + k0 + g * 8];
      acc[tt] = __builtin_amdgcn_mfma_f32_16x16x32_bf16(a, bvv, acc[tt], 0, 0, 0);
    }
  }
  const int b = bh / Hh, h = bh % Hh;
#pragma unroll
  for (int tt = 0; tt < 4; tt++)
#pragma unroll
    for (int e = 0; e < 4; e++) {
      int nrow = rowbase + g * 4 + e;
      oh[((size_t)(b * Nn + nrow)) * Cc + h * HD + (tt << 4) + r] = (bf16_t)acc[tt][e];
    }
}

// -------------------------------------------------------------------------
extern "C" void kernel_launch(void* const* d_in, const int* in_sizes, int n_in,
                              void* d_out, int out_size, void* d_ws, size_t ws_size,
                              hipStream_t stream) {
  const float* x      = (const float*)d_in[0];
  const float* prev   = (const float*)d_in[1];
  const float* qkv_w  = (const float*)d_in[2];
  const float* proj_w = (const float*)d_in[3];
  const float* proj_b = (const float*)d_in[4];
  const float* bp_w1  = (const float*)d_in[5];
  const float* bp_b1  = (const float*)d_in[6];
  const float* bp_w2  = (const float*)d_in[7];
  const float* bp_w2b = (const float*)d_in[8];

  float* out0 = (float*)d_out;
  float* cur  = out0 + OUT0;

  // workspace layout (bytes)
  char* ws = (char*)d_ws;
  bf16_t* xb    = (bf16_t*)(ws + 0);          //  6291456
  bf16_t* qwb   = (bf16_t*)(ws + 6291456);    //  3538944
  bf16_t* pwb   = (bf16_t*)(ws + 9830400);    //  1179648
  bf16_t* qbf   = (bf16_t*)(ws + 11010048);   //  6291456
  bf16_t* kbf   = (bf16_t*)(ws + 17301504);   //  6291456
  bf16_t* vtb   = (bf16_t*)(ws + 23592960);   //  6291456
  float*  bias4 = (float*)(ws + 29884416);    //   786432
  bf16_t* ohb   = (bf16_t*)(ws + 30670848);   //  6291456  -> end 36962304
  if (ws_size < 36962304) return;  // insufficient scratch: fail loudly (output stays poisoned)

  convert_all<<<5376, 256, 0, stream>>>(x, qkv_w, proj_w, xb, qwb, pwb);
  gemm_bt<0><<<(4096 / 128) * (2304 / 128), 256, 0, stream>>>(
      xb, qwb, 2304, 768, qbf, kbf, vtb, nullptr, nullptr);
  attn_softmax<<<48 * 64, 256, 0, stream>>>(qbf, kbf, cur);
  bias_mlp<<<49152 / 8, 256, 0, stream>>>(qbf, kbf, bp_w1, bp_b1, bp_w2, bp_w2b, bias4);
  blend_av<<<48 * 16, 256, 0, stream>>>(cur, prev, bias4, vtb, ohb);
  gemm_bt<1><<<(4096 / 128) * (768 / 128), 256, 0, stream>>>(
      ohb, pwb, 768, 768, nullptr, nullptr, nullptr, out0, proj_b);
}

// Round 2
// 249.141 us; speedup vs baseline: 1.1262x; 1.1262x over previous
//
#include <hip/hip_runtime.h>

typedef __bf16 bf16_t;
typedef __bf16 bf16x8 __attribute__((ext_vector_type(8)));
typedef __bf16 bf16x4 __attribute__((ext_vector_type(4)));
typedef float f32x4 __attribute__((ext_vector_type(4)));

static constexpr int Bb = 4, Hh = 12, Nn = 1024, Cc = 768, HD = 64;
static constexpr int OUT0 = Bb * Nn * Cc;  // 3145728 floats

// ---------------- convert fp32 -> bf16 (x, qkv_w, proj_w) ----------------
__global__ __launch_bounds__(256) void convert_all(
    const float* __restrict__ x, const float* __restrict__ qw, const float* __restrict__ pw,
    bf16_t* __restrict__ xb, bf16_t* __restrict__ qwb, bf16_t* __restrict__ pwb) {
  const int NX = (Bb * Nn * Cc) / 4;  // 786432 float4s
  const int NQ = (3 * Cc * Cc) / 4;   // 442368
  int i = blockIdx.x * 256 + threadIdx.x;
  const float4* src;
  bf16_t* dst;
  int off;
  if (i < NX) { src = (const float4*)x; dst = xb; off = i; }
  else if (i < NX + NQ) { src = (const float4*)qw; dst = qwb; off = i - NX; }
  else { src = (const float4*)pw; dst = pwb; off = i - NX - NQ; }
  float4 v = src[off];
  bf16x4 o;
  o[0] = (bf16_t)v.x; o[1] = (bf16_t)v.y; o[2] = (bf16_t)v.z; o[3] = (bf16_t)v.w;
  *(bf16x4*)(dst + (size_t)off * 4) = o;
}

// ---------------- 128x128-tile bf16 MFMA GEMM, C[m,c] = A[m,:]*B[c,:] -----
template <int MODE>
__global__ __launch_bounds__(256) void gemm_bt(
    const bf16_t* __restrict__ A, const bf16_t* __restrict__ Bm, int N, int K,
    bf16_t* __restrict__ q_bf, bf16_t* __restrict__ k_bf, bf16_t* __restrict__ vT_bf,
    float* __restrict__ outF, const float* __restrict__ bias) {
  __shared__ bf16_t As[128 * 40];
  __shared__ bf16_t Bs[128 * 40];
  const int tid = threadIdx.x;
  const int lane = tid & 63;
  const int w = tid >> 6;
  const int wr = w >> 1, wc = w & 1;
  const int g = lane >> 4, r = lane & 15;
  const int ntiles = N >> 7;
  const int m0 = (blockIdx.x / ntiles) << 7;
  const int n0 = (blockIdx.x % ntiles) << 7;

  const f32x4 fz = {0.f, 0.f, 0.f, 0.f};
  f32x4 acc[4][4];
#pragma unroll
  for (int i = 0; i < 4; i++)
#pragma unroll
    for (int j = 0; j < 4; j++) acc[i][j] = fz;

  for (int k0 = 0; k0 < K; k0 += 32) {
#pragma unroll
    for (int p = 0; p < 2; p++) {
      int idx = tid + (p << 8);
      int row = idx >> 2;
      int kof = (idx & 3) << 3;
      *(bf16x8*)&As[row * 40 + kof] = *(const bf16x8*)&A[(size_t)(m0 + row) * K + k0 + kof];
      *(bf16x8*)&Bs[row * 40 + kof] = *(const bf16x8*)&Bm[(size_t)(n0 + row) * K + k0 + kof];
    }
    __syncthreads();
    bf16x8 af[4], bfv[4];
#pragma unroll
    for (int i = 0; i < 4; i++) af[i] = *(const bf16x8*)&As[(wr * 64 + i * 16 + r) * 40 + g * 8];
#pragma unroll
    for (int j = 0; j < 4; j++) bfv[j] = *(const bf16x8*)&Bs[(wc * 64 + j * 16 + r) * 40 + g * 8];
#pragma unroll
    for (int i = 0; i < 4; i++)
#pragma unroll
      for (int j = 0; j < 4; j++)
        acc[i][j] = __builtin_amdgcn_mfma_f32_16x16x32_bf16(af[i], bfv[j], acc[i][j], 0, 0, 0);
    __syncthreads();
  }

#pragma unroll
  for (int i = 0; i < 4; i++) {
#pragma unroll
    for (int j = 0; j < 4; j++) {
      int c = n0 + wc * 64 + j * 16 + r;
#pragma unroll
      for (int e = 0; e < 4; e++) {
        int mrow = m0 + wr * 64 + i * 16 + g * 4 + e;
        float val = acc[i][j][e];
        if constexpr (MODE == 0) {
          int which = c / 768;
          int cc = c - which * 768;
          int h = cc >> 6, d = cc & 63;
          int b = mrow >> 10, n = mrow & 1023;
          size_t bh = (size_t)(b * Hh + h);
          if (which == 0)      q_bf[(bh * Nn + n) * HD + d] = (bf16_t)val;
          else if (which == 1) k_bf[(bh * Nn + n) * HD + d] = (bf16_t)val;
          else                 vT_bf[(bh * HD + d) * Nn + n] = (bf16_t)val;
        } else {
          outF[(size_t)mrow * N + c] = val + bias[c];
        }
      }
    }
  }
}

// ---------------- per-(b,h,n) bias MLP -> {1+b0, b1, -b2/N, 0} -----------
__global__ __launch_bounds__(256) void bias_mlp(
    const bf16_t* __restrict__ qb, const bf16_t* __restrict__ kb,
    const float* __restrict__ w1, const float* __restrict__ b1,
    const float* __restrict__ w2, const float* __restrict__ b2,
    float* __restrict__ bias4) {
  __shared__ float w1s[32 * 129];
  __shared__ float qks[8][128];
  __shared__ float h1s[8][32];
  const int t = threadIdx.x;
#pragma unroll
  for (int p = 0; p < 16; p++) {
    int idx = p * 256 + t;
    w1s[(idx >> 7) * 129 + (idx & 127)] = w1[idx];
  }
  const int rl = t >> 5, u = t & 31;
  const int rowg = blockIdx.x * 8 + rl;
  {
    int i4 = u * 4;
    const bf16_t* src = (i4 < 64) ? (qb + (size_t)rowg * HD + i4)
                                  : (kb + (size_t)rowg * HD + (i4 - 64));
    bf16x4 vv = *(const bf16x4*)src;
#pragma unroll
    for (int z = 0; z < 4; z++) qks[rl][i4 + z] = (float)vv[z];
  }
  __syncthreads();
  float accv = b1[u];
#pragma unroll 8
  for (int i = 0; i < 128; i++) accv += qks[rl][i] * w1s[u * 129 + i];
  h1s[rl][u] = fmaxf(accv, 0.f);
  __syncthreads();
  if (u < 4) {
    float outv = 0.f;
    if (u < 3) {
      float s = b2[u];
#pragma unroll
      for (int j = 0; j < 32; j++) s += w2[u * 32 + j] * h1s[rl][j];
      float v = fabsf(s);
      outv = (u == 0) ? (1.f + v) : ((u == 1) ? v : -v * (1.f / (float)Nn));
    }
    bias4[(size_t)rowg * 4 + u] = outv;
  }
}

// ---------------- fused: QK^T -> softmax -> cur write -> blend -> PV -----
// block: 256 thr (4 waves), handles 16 rows of one (b,h).
// Phase 1: wave w computes P rows 0..15, cols [256w, 256w+256); writes cur.
// Phase 2: cooperative coalesced prev read + blend (RMW LDS bf16 P).
// Phase 3: wave w computes out cols [16w,16w+16) over K=1024 (4 indep chains).
__global__ __launch_bounds__(256) void attn_fused(
    const bf16_t* __restrict__ qb, const bf16_t* __restrict__ kb,
    const bf16_t* __restrict__ vT, const float* __restrict__ prev,
    const float* __restrict__ bias4, float* __restrict__ cur,
    bf16_t* __restrict__ oh) {
  __shared__ bf16_t Pb[16 * 1024];   // blended probs, XOR-swizzled cols
  __shared__ float redmax[16][4];
  __shared__ float redsum[16][4];
  const int bid = blockIdx.x;
  const int bh = bid >> 6, mt = bid & 63;
  const int tid = threadIdx.x;
  const int lane = tid & 63, w = tid >> 6;
  const int g = lane >> 4, r = lane & 15;
  const int row0 = mt << 4;

  // ---- Phase 1: QK^T + softmax ----
  const bf16_t* qp = qb + ((size_t)bh * Nn + row0) * HD;
  const bf16_t* kp = kb + (size_t)bh * Nn * HD;
  bf16x8 a0 = *(const bf16x8*)&qp[r * HD + g * 8];
  bf16x8 a1 = *(const bf16x8*)&qp[r * HD + g * 8 + 32];
  const f32x4 fz = {0.f, 0.f, 0.f, 0.f};
  f32x4 acc[16];
#pragma unroll
  for (int t = 0; t < 16; t++) {
    int col = (w << 8) + (t << 4) + r;
    bf16x8 b0 = *(const bf16x8*)&kp[(size_t)col * HD + g * 8];
    bf16x8 b1 = *(const bf16x8*)&kp[(size_t)col * HD + g * 8 + 32];
    f32x4 z = __builtin_amdgcn_mfma_f32_16x16x32_bf16(a0, b0, fz, 0, 0, 0);
    acc[t] = __builtin_amdgcn_mfma_f32_16x16x32_bf16(a1, b1, z, 0, 0, 0);
  }
  const float scale = 0.125f;
  float mj[4] = {-3.0e38f, -3.0e38f, -3.0e38f, -3.0e38f};
#pragma unroll
  for (int t = 0; t < 16; t++)
#pragma unroll
    for (int e = 0; e < 4; e++) {
      acc[t][e] *= scale;
      mj[e] = fmaxf(mj[e], acc[t][e]);
    }
#pragma unroll
  for (int s = 1; s < 16; s <<= 1)
#pragma unroll
    for (int e = 0; e < 4; e++) mj[e] = fmaxf(mj[e], __shfl_xor(mj[e], s, 64));
  if (r == 0) {
#pragma unroll
    for (int e = 0; e < 4; e++) redmax[g * 4 + e][w] = mj[e];
  }
  __syncthreads();
  float rm[4];
#pragma unroll
  for (int e = 0; e < 4; e++) {
    float v = fmaxf(redmax[g * 4 + e][0], redmax[g * 4 + e][1]);
    rm[e] = fmaxf(v, fmaxf(redmax[g * 4 + e][2], redmax[g * 4 + e][3]));
  }
  float sj[4] = {0.f, 0.f, 0.f, 0.f};
#pragma unroll
  for (int t = 0; t < 16; t++)
#pragma unroll
    for (int e = 0; e < 4; e++) {
      float ev = __expf(acc[t][e] - rm[e]);
      acc[t][e] = ev;
      sj[e] += ev;
    }
#pragma unroll
  for (int s = 1; s < 16; s <<= 1)
#pragma unroll
    for (int e = 0; e < 4; e++) sj[e] += __shfl_xor(sj[e], s, 64);
  if (r == 0) {
#pragma unroll
    for (int e = 0; e < 4; e++) redsum[g * 4 + e][w] = sj[e];
  }
  __syncthreads();
  float inv[4];
#pragma unroll
  for (int e = 0; e < 4; e++)
    inv[e] = 1.f / (redsum[g * 4 + e][0] + redsum[g * 4 + e][1] +
                    redsum[g * 4 + e][2] + redsum[g * 4 + e][3]);
  // write cur (fp32, from registers) + stash bf16 P in LDS (swizzled)
  float* op = cur + (size_t)bh * Nn * Nn;
#pragma unroll
  for (int t = 0; t < 16; t++) {
    int col = (w << 8) + (t << 4) + r;
#pragma unroll
    for (int e = 0; e < 4; e++) {
      float p = acc[t][e] * inv[e];
      int row = g * 4 + e;
      op[(size_t)(row0 + row) * Nn + col] = p;
      Pb[row * 1024 + (col ^ ((row & 7) << 3))] = (bf16_t)p;
    }
  }
  __syncthreads();

  // ---- Phase 2: coalesced prev read + blend (RMW LDS) ----
  const float* pp = prev + (size_t)bh * Nn * Nn + (size_t)row0 * Nn;
  const float* bp = bias4 + ((size_t)(bh << 10) + row0) * 4;
#pragma unroll
  for (int i = 0; i < 16; i++) {
    float4 pv = *(const float4*)&pp[(size_t)i * Nn + tid * 4];
    float4 bv = *(const float4*)&bp[i * 4];
    int ci = (tid * 4) ^ ((i & 7) << 3);
    bf16x4 pbv = *(bf16x4*)&Pb[i * 1024 + ci];
    bf16x4 nb;
    nb[0] = (bf16_t)(bv.x * (float)pbv[0] + bv.y * pv.x + bv.z);
    nb[1] = (bf16_t)(bv.x * (float)pbv[1] + bv.y * pv.y + bv.z);
    nb[2] = (bf16_t)(bv.x * (float)pbv[2] + bv.y * pv.z + bv.z);
    nb[3] = (bf16_t)(bv.x * (float)pbv[3] + bv.y * pv.w + bv.z);
    *(bf16x4*)&Pb[i * 1024 + ci] = nb;
  }
  __syncthreads();

  // ---- Phase 3: PV. wave w -> out cols [16w,16w+16), 4 indep K-chains ----
  const bf16_t* vp = vT + ((size_t)bh * HD + (w << 4) + r) * Nn;
  f32x4 c0 = fz, c1 = fz, c2 = fz, c3 = fz;
#pragma unroll
  for (int ks = 0; ks < 8; ks++) {
    int kA = ks * 32;
    bf16x8 afA = *(bf16x8*)&Pb[r * 1024 + ((kA + g * 8) ^ ((r & 7) << 3))];
    bf16x8 afB = *(bf16x8*)&Pb[r * 1024 + ((256 + kA + g * 8) ^ ((r & 7) << 3))];
    bf16x8 afC = *(bf16x8*)&Pb[r * 1024 + ((512 + kA + g * 8) ^ ((r & 7) << 3))];
    bf16x8 afD = *(bf16x8*)&Pb[r * 1024 + ((768 + kA + g * 8) ^ ((r & 7) << 3))];
    bf16x8 bA = *(const bf16x8*)&vp[kA + g * 8];
    bf16x8 bB = *(const bf16x8*)&vp[256 + kA + g * 8];
    bf16x8 bC = *(const bf16x8*)&vp[512 + kA + g * 8];
    bf16x8 bD = *(const bf16x8*)&vp[768 + kA + g * 8];
    c0 = __builtin_amdgcn_mfma_f32_16x16x32_bf16(afA, bA, c0, 0, 0, 0);
    c1 = __builtin_amdgcn_mfma_f32_16x16x32_bf16(afB, bB, c1, 0, 0, 0);
    c2 = __builtin_amdgcn_mfma_f32_16x16x32_bf16(afC, bC, c2, 0, 0, 0);
    c3 = __builtin_amdgcn_mfma_f32_16x16x32_bf16(afD, bD, c3, 0, 0, 0);
  }
  f32x4 osum = (c0 + c1) + (c2 + c3);
  const int b = bh / Hh, h = bh % Hh;
#pragma unroll
  for (int e = 0; e < 4; e++) {
    int nrow = row0 + g * 4 + e;
    oh[((size_t)(b * Nn + nrow)) * Cc + h * HD + (w << 4) + r] = (bf16_t)osum[e];
  }
}

// -------------------------------------------------------------------------
extern "C" void kernel_launch(void* const* d_in, const int* in_sizes, int n_in,
                              void* d_out, int out_size, void* d_ws, size_t ws_size,
                              hipStream_t stream) {
  const float* x      = (const float*)d_in[0];
  const float* prev   = (const float*)d_in[1];
  const float* qkv_w  = (const float*)d_in[2];
  const float* proj_w = (const float*)d_in[3];
  const float* proj_b = (const float*)d_in[4];
  const float* bp_w1  = (const float*)d_in[5];
  const float* bp_b1  = (const float*)d_in[6];
  const float* bp_w2  = (const float*)d_in[7];
  const float* bp_w2b = (const float*)d_in[8];

  float* out0 = (float*)d_out;
  float* cur  = out0 + OUT0;

  char* ws = (char*)d_ws;
  bf16_t* xb    = (bf16_t*)(ws + 0);
  bf16_t* qwb   = (bf16_t*)(ws + 6291456);
  bf16_t* pwb   = (bf16_t*)(ws + 9830400);
  bf16_t* qbf   = (bf16_t*)(ws + 11010048);
  bf16_t* kbf   = (bf16_t*)(ws + 17301504);
  bf16_t* vtb   = (bf16_t*)(ws + 23592960);
  float*  bias4 = (float*)(ws + 29884416);
  bf16_t* ohb   = (bf16_t*)(ws + 30670848);
  if (ws_size < 36962304) return;

  convert_all<<<5376, 256, 0, stream>>>(x, qkv_w, proj_w, xb, qwb, pwb);
  gemm_bt<0><<<(4096 / 128) * (2304 / 128), 256, 0, stream>>>(
      xb, qwb, 2304, 768, qbf, kbf, vtb, nullptr, nullptr);
  bias_mlp<<<49152 / 8, 256, 0, stream>>>(qbf, kbf, bp_w1, bp_b1, bp_w2, bp_w2b, bias4);
  attn_fused<<<48 * 64, 256, 0, stream>>>(qbf, kbf, vtb, prev, bias4, cur, ohb);
  gemm_bt<1><<<(4096 / 128) * (768 / 128), 256, 0, stream>>>(
      ohb, pwb, 768, 768, nullptr, nullptr, nullptr, out0, proj_b);
}